// Round 11
// baseline (331.035 us; speedup 1.0000x reference)
//
#include <hip/hip_runtime.h>
#include <stdint.h>

typedef unsigned short u16;
typedef __bf16 bf16x8 __attribute__((ext_vector_type(8)));
typedef float f32x4 __attribute__((ext_vector_type(4)));

#define K_DIM 4096
#define N_OUT 4096
#define M_ROWS 8192

// ---------- helpers ----------

__device__ __forceinline__ u16 f2bf(float f) {
    uint32_t u = __builtin_bit_cast(uint32_t, f);
    u += 0x7fffu + ((u >> 16) & 1u);
    return (u16)(u >> 16);
}

__device__ __forceinline__ void gload_lds16(const void* g, void* l) {
    __builtin_amdgcn_global_load_lds(
        (const __attribute__((address_space(1))) void*)g,
        (__attribute__((address_space(3))) void*)l,
        16, 0, 0);
}

__device__ __forceinline__ int mask_is_int32(const void* maskp) {
    const uint32_t* u = (const uint32_t*)maskp;
    int ok = 1;
#pragma unroll
    for (int g = 0; g < 16; ++g) ok &= (u[g] <= 1u);
    return ok;
}

// ---------- fused prep kernel (r9; ~75us, at BW floor) ----------
// blocks [0, 16384): x f32 -> bf16 (8 elems/thread)
// blocks [16384, 24576): W_eff = mask ? (wq - qzero)*qscale : theta -> bf16

__global__ __launch_bounds__(256) void prep_kernel(const float* __restrict__ x,
                                                   u16* __restrict__ xb,
                                                   const int* __restrict__ wq,
                                                   const float* __restrict__ qscale,
                                                   const float* __restrict__ qzero,
                                                   const float* __restrict__ theta,
                                                   const void* __restrict__ maskp,
                                                   u16* __restrict__ wb) {
    if (blockIdx.x < 16384) {
        size_t t = (size_t)blockIdx.x * 256 + threadIdx.x;
        const float4* p = (const float4*)x + t * 2;
        float4 a = p[0], b = p[1];
        union { u16 u[8]; uint4 v; } o;
        o.u[0] = f2bf(a.x); o.u[1] = f2bf(a.y); o.u[2] = f2bf(a.z); o.u[3] = f2bf(a.w);
        o.u[4] = f2bf(b.x); o.u[5] = f2bf(b.y); o.u[6] = f2bf(b.z); o.u[7] = f2bf(b.w);
        ((uint4*)xb)[t] = o.v;
    } else {
        const int mi32 = mask_is_int32(maskp);
        size_t t = (size_t)(blockIdx.x - 16384) * 256 + threadIdx.x;
        size_t base = t * 8;
        int o = (int)(base >> 12);
        float s = qscale[o], z = qzero[o];

        int4 q0 = ((const int4*)wq)[t * 2];
        int4 q1 = ((const int4*)wq)[t * 2 + 1];
        float4 th0 = ((const float4*)theta)[t * 2];
        float4 th1 = ((const float4*)theta)[t * 2 + 1];

        int mv[8];
        if (mi32) {
            int4 m0 = ((const int4*)maskp)[t * 2];
            int4 m1 = ((const int4*)maskp)[t * 2 + 1];
            mv[0] = m0.x; mv[1] = m0.y; mv[2] = m0.z; mv[3] = m0.w;
            mv[4] = m1.x; mv[5] = m1.y; mv[6] = m1.z; mv[7] = m1.w;
        } else {
            uint2 mm = ((const uint2*)maskp)[t];
#pragma unroll
            for (int j = 0; j < 4; ++j) mv[j] = (mm.x >> (8 * j)) & 0xff;
#pragma unroll
            for (int j = 0; j < 4; ++j) mv[4 + j] = (mm.y >> (8 * j)) & 0xff;
        }

        float w[8];
        w[0] = mv[0] ? ((float)q0.x - z) * s : th0.x;
        w[1] = mv[1] ? ((float)q0.y - z) * s : th0.y;
        w[2] = mv[2] ? ((float)q0.z - z) * s : th0.z;
        w[3] = mv[3] ? ((float)q0.w - z) * s : th0.w;
        w[4] = mv[4] ? ((float)q1.x - z) * s : th1.x;
        w[5] = mv[5] ? ((float)q1.y - z) * s : th1.y;
        w[6] = mv[6] ? ((float)q1.z - z) * s : th1.z;
        w[7] = mv[7] ? ((float)q1.w - z) * s : th1.w;

        union { u16 u[8]; uint4 v; } ob;
#pragma unroll
        for (int j = 0; j < 8; ++j) ob.u[j] = f2bf(w[j]);
        ((uint4*)wb)[t] = ob.v;
    }
}

// ---------- 256x256 GEMM, 16x16x32, 4 fat phases / 2 tiles (r11) ----------
//
// Change vs r10: phase = ONE K=32 plane x BOTH MH halves = 32 MFMA + 12
// ds_read_b128 (was 16 MFMA + 4-8 reads). Halves the per-iteration barrier /
// fixed-overhead count; per-phase overhead amortized over 2x MFMA work.
// LDS layout/addresses/swizzle BYTE-IDENTICAL to r3/r7 (frozen geometry:
// phys_slot = log_slot ^ ((row>>1)&3); write via pre-swizzled global chunk
// (l&3)^((l>>3)&3); 0 conflicts measured r3/r7/r9/r10).
// Phase p (iter j, tiles T0=2j[buf0], T1=2j+1[buf1], T2=2j+2, T3=2j+3):
//   P1: read b0k0 (af MH0/MH1 + bf); MFMA32; VMW4; stage b1k1<-T1;  BAR
//   P2: read b0k1;                   MFMA32; VMW4; stage b0k0<-T2&; BAR
//   P3: read b1k0;                   MFMA32; VMW4; stage b0k1<-T2&; BAR
//   P4: read b1k1;                   MFMA32; VMW4; stage b1k0<-T3&; BAR
// Hazards (verified): each stage's target plane's last reader = 1 barrier
// earlier (same-phase readers read a disjoint plane; cross-wave OK since the
// stage is issued after the barrier its readers crossed). Each phase's reads
// were staged >=3 phases earlier and drained by the VMW4 one phase earlier
// (>=1 barrier between drain and read, all waves). vmcnt uniform: top-of-phase
// outstanding = 8, VMW4 drains oldest batch, stage refills to 8 — never 0.
// Prologue = 3 batches (b0k0,b0k1,b1k0) + vmcnt(8) (drains batch1) + BAR.
// Registers: 12 frag regs (48 VGPR) — UNDER r10's 16; launch_bounds(512,2)
// (r8: (512,4) = spill cliff, never again).

__global__ __launch_bounds__(512, 2) void gemm8_kernel(const u16* __restrict__ xb,
                                                       const u16* __restrict__ wb,
                                                       const float* __restrict__ bias,
                                                       float* __restrict__ out) {
    __shared__ u16 lds[65536];  // 128 KiB: A planes [0,32768), B planes [32768,65536)

    const int tid = threadIdx.x;
    const int lane = tid & 63, wave = tid >> 6;
    const int wm = wave >> 2, wn = wave & 3;
    const int n0 = blockIdx.x * 256;
    const int m0 = blockIdx.y * 256;

    // fragment-read addressing (u16 units) — r3 proven pattern
    const int a_r = wm * 128 + (lane & 15);
    const int b_r = wn * 64 + (lane & 15);
    const int rslot = ((lane >> 4) ^ ((lane >> 1) & 3)) * 8;

    // stage addressing: wave w instr i covers chunk c=w*2+i = rows [c*16,+16)
    const int ch0 = wave * 2, ch1 = ch0 + 1;
    const int sRow = lane >> 2;
    const int sK = (((lane & 3) ^ ((lane >> 3) & 3)) * 8);
    const u16* gA0 = xb + (size_t)(m0 + ch0 * 16 + sRow) * K_DIM + sK;
    const u16* gA1 = xb + (size_t)(m0 + ch1 * 16 + sRow) * K_DIM + sK;
    const u16* gB0 = wb + (size_t)(n0 + ch0 * 16 + sRow) * K_DIM + sK;
    const u16* gB1 = wb + (size_t)(n0 + ch1 * 16 + sRow) * K_DIM + sK;

    f32x4 acc[8][4];
    const f32x4 zero = {0.f, 0.f, 0.f, 0.f};
#pragma unroll
    for (int m = 0; m < 8; ++m)
#pragma unroll
        for (int n = 0; n < 4; ++n) acc[m][n] = zero;

    // fragment registers (single set: af MH0 = af0-3, af MH1 = af4-7, bf0-3)
    bf16x8 af0, af1, af2, af3, af4, af5, af6, af7, bf0, bf1, bf2, bf3;

#define SA(BUF, KH, KT) { \
    const size_t kofs = (size_t)((KT) * 64 + (KH) * 32); \
    const int pl = ((BUF) * 2 + (KH)) * 8192; \
    gload_lds16(gA0 + kofs, &lds[pl + ch0 * 512]); \
    gload_lds16(gA1 + kofs, &lds[pl + ch1 * 512]); }
#define SB(BUF, KH, KT) { \
    const size_t kofs = (size_t)((KT) * 64 + (KH) * 32); \
    const int pl = 32768 + ((BUF) * 2 + (KH)) * 8192; \
    gload_lds16(gB0 + kofs, &lds[pl + ch0 * 512]); \
    gload_lds16(gB1 + kofs, &lds[pl + ch1 * 512]); }
#define DA(BUF, KS, MH, R0, R1, R2, R3) { \
    const int pa = ((BUF) * 2 + (KS)) * 8192 + (a_r + (MH) * 64) * 32 + rslot; \
    R0 = *(const bf16x8*)&lds[pa]; \
    R1 = *(const bf16x8*)&lds[pa + 512]; \
    R2 = *(const bf16x8*)&lds[pa + 1024]; \
    R3 = *(const bf16x8*)&lds[pa + 1536]; }
#define DB(BUF, KS) { \
    const int pb = 32768 + ((BUF) * 2 + (KS)) * 8192 + b_r * 32 + rslot; \
    bf0 = *(const bf16x8*)&lds[pb]; \
    bf1 = *(const bf16x8*)&lds[pb + 512]; \
    bf2 = *(const bf16x8*)&lds[pb + 1024]; \
    bf3 = *(const bf16x8*)&lds[pb + 1536]; }
#define MF(A, B, C) __builtin_amdgcn_mfma_f32_16x16x32_bf16(A, B, C, 0, 0, 0)
#define MROW(M, AF) { \
    acc[M][0] = MF(AF, bf0, acc[M][0]); \
    acc[M][1] = MF(AF, bf1, acc[M][1]); \
    acc[M][2] = MF(AF, bf2, acc[M][2]); \
    acc[M][3] = MF(AF, bf3, acc[M][3]); }
#define MFMA32() { \
    __builtin_amdgcn_s_setprio(1); \
    MROW(0, af0) MROW(1, af1) MROW(2, af2) MROW(3, af3) \
    MROW(4, af4) MROW(5, af5) MROW(6, af6) MROW(7, af7) \
    __builtin_amdgcn_s_setprio(0); }
#define BAR() __builtin_amdgcn_s_barrier()
#define SCHED0() __builtin_amdgcn_sched_barrier(0)
#define VMW4() asm volatile("s_waitcnt vmcnt(4)" ::: "memory")

    // one fat phase: read plane (BUF,KS), 32 MFMA, counted drain, stage one
    // plane-pair (STB,STK) <- tile STT, barrier.
#define PHASE(BUF, KS, STB, STK, STT) { \
    DA(BUF, KS, 0, af0, af1, af2, af3); \
    DB(BUF, KS); \
    DA(BUF, KS, 1, af4, af5, af6, af7); \
    MFMA32(); \
    VMW4(); \
    SA(STB, STK, STT); SB(STB, STK, STT); \
    SCHED0(); BAR(); }

    // prologue: batches b0k0(T0), b0k1(T0), b1k0(T1); drain batch1; barrier
    SA(0, 0, 0); SB(0, 0, 0);
    SA(0, 1, 0); SB(0, 1, 0);
    SA(1, 0, 1); SB(1, 0, 1);
    asm volatile("s_waitcnt vmcnt(8)" ::: "memory");
    BAR();

#pragma unroll 1
    for (int j = 0; j < K_DIM / 128; ++j) {
        const int t1 = 2 * j + 1;
        const int t2 = (2 * j + 2) & 63;
        const int t3 = (2 * j + 3) & 63;
        PHASE(0, 0, 1, 1, t1);   // compute T0.k0; stage b1k1 <- T1
        PHASE(0, 1, 0, 0, t2);   // compute T0.k1; stage b0k0 <- T2
        PHASE(1, 0, 0, 1, t2);   // compute T1.k0; stage b0k1 <- T2
        PHASE(1, 1, 1, 0, t3);   // compute T1.k1; stage b1k0 <- T3
    }

    // drain trailing prefetches so no gload lands in deallocated LDS
    asm volatile("s_waitcnt vmcnt(0)" ::: "memory");

    // epilogue: C/D layout col=lane&15, row=(lane>>4)*4+reg
    const int rowBase = m0 + wm * 128 + ((lane >> 4) << 2);
    const int colBase = n0 + wn * 64 + (lane & 15);
#pragma unroll
    for (int n = 0; n < 4; ++n) {
        const int col = colBase + n * 16;
        const float bv = bias[col];
#pragma unroll
        for (int m = 0; m < 8; ++m) {
            const f32x4 v = acc[m][n];
            float* o = out + (size_t)(rowBase + m * 16) * N_OUT + col;
            o[0] = v[0] + bv;
            o[N_OUT] = v[1] + bv;
            o[2 * N_OUT] = v[2] + bv;
            o[3 * N_OUT] = v[3] + bv;
        }
    }
#undef SA
#undef SB
#undef DA
#undef DB
#undef MF
#undef MROW
#undef MFMA32
#undef BAR
#undef SCHED0
#undef VMW4
#undef PHASE
}

// ---------- correct-but-slow fallback (only if ws too small) ----------

__global__ __launch_bounds__(256) void fallback_kernel(const float* __restrict__ x,
                                                       const int* __restrict__ wq,
                                                       const float* __restrict__ qscale,
                                                       const float* __restrict__ qzero,
                                                       const float* __restrict__ theta,
                                                       const void* __restrict__ maskp,
                                                       const float* __restrict__ bias,
                                                       float* __restrict__ out) {
    __shared__ float xs[64][17];
    __shared__ float wsh[64][17];
    const int mi32 = mask_is_int32(maskp);
    const int n0 = blockIdx.x * 64, m0 = blockIdx.y * 64;
    const int t = threadIdx.x;
    const int tr = t >> 4, tc = t & 15;
    float acc[4][4] = {};

    for (int k0 = 0; k0 < K_DIM; k0 += 16) {
#pragma unroll
        for (int j = 0; j < 4; ++j) {
            int e = t * 4 + j;
            int r = e >> 4, c = e & 15;
            xs[r][c] = x[(size_t)(m0 + r) * K_DIM + k0 + c];
            int o = n0 + r;
            size_t idx = (size_t)o * K_DIM + k0 + c;
            float dq = ((float)wq[idx] - qzero[o]) * qscale[o];
            int mv = mi32 ? ((const int*)maskp)[idx] : ((const unsigned char*)maskp)[idx];
            wsh[r][c] = mv ? dq : theta[idx];
        }
        __syncthreads();
#pragma unroll
        for (int kk = 0; kk < 16; ++kk) {
            float a4[4], b4[4];
#pragma unroll
            for (int i = 0; i < 4; ++i) a4[i] = xs[tr * 4 + i][kk];
#pragma unroll
            for (int i = 0; i < 4; ++i) b4[i] = wsh[tc * 4 + i][kk];
#pragma unroll
            for (int i = 0; i < 4; ++i)
#pragma unroll
                for (int j = 0; j < 4; ++j) acc[i][j] += a4[i] * b4[j];
        }
        __syncthreads();
    }
#pragma unroll
    for (int i = 0; i < 4; ++i)
#pragma unroll
        for (int j = 0; j < 4; ++j)
            out[(size_t)(m0 + tr * 4 + i) * N_OUT + n0 + tc * 4 + j] =
                acc[i][j] + bias[n0 + tc * 4 + j];
}

// ---------- launch ----------

extern "C" void kernel_launch(void* const* d_in, const int* in_sizes, int n_in,
                              void* d_out, int out_size, void* d_ws, size_t ws_size,
                              hipStream_t stream) {
    const float* x      = (const float*)d_in[0];
    const int*   wq     = (const int*)d_in[1];
    const float* qscale = (const float*)d_in[2];
    const float* qzero  = (const float*)d_in[3];
    const float* theta  = (const float*)d_in[4];
    const void*  mask   = d_in[5];
    const float* bias   = (const float*)d_in[6];
    float* out = (float*)d_out;

    const size_t xb_bytes = (size_t)M_ROWS * K_DIM * 2;
    const size_t wb_bytes = (size_t)N_OUT * K_DIM * 2;

    if (ws_size >= xb_bytes + wb_bytes) {
        u16* xb = (u16*)d_ws;
        u16* wb = (u16*)((char*)d_ws + xb_bytes);
        prep_kernel<<<24576, 256, 0, stream>>>(x, xb, wq, qscale, qzero, theta, mask, wb);
        dim3 grid(N_OUT / 256, M_ROWS / 256);
        gemm8_kernel<<<grid, 512, 0, stream>>>(xb, wb, bias, out);
    } else {
        dim3 grid(N_OUT / 64, M_ROWS / 64);
        fallback_kernel<<<grid, 256, 0, stream>>>(x, wq, qscale, qzero, theta, mask, bias, out);
    }
}